// Round 1
// baseline (454.890 us; speedup 1.0000x reference)
//
#include <hip/hip_runtime.h>

// Problem: B=8, C=3, H=1024, W=1024, f32 stencil with circular rolls.
// m_r, invSigma_r outputs concatenated in d_out.

#define HH 1024
#define WW 1024
#define NPLANES 24          // B*C
#define VECS_PER_ROW (WW/4) // 256

__global__ __launch_bounds__(256) void rmodule_kernel(
    const float* __restrict__ diagAtA,
    const float* __restrict__ Aty,
    const float* __restrict__ mk,
    const float* __restrict__ lambdak,
    const float* __restrict__ gamma_n_p,
    const float* __restrict__ gamma_p_p,
    const int*   __restrict__ scale_p,
    float* __restrict__ out_m_r,
    float* __restrict__ out_invSigma)
{
    const int idx = blockIdx.x * blockDim.x + threadIdx.x;
    const int total_vec = NPLANES * HH * VECS_PER_ROW;
    if (idx >= total_vec) return;

    const float gn = gamma_n_p[0];
    const float gp = gamma_p_p[0];
    const int scale = scale_p[0];

    const int row   = idx >> 8;          // idx / VECS_PER_ROW (256)
    const int w0    = (idx & 255) << 2;  // starting w of this float4
    const int h     = row & (HH - 1);
    const int plane = row >> 10;         // row / HH

    const int base = plane * HH * WW;
    const int rowC = base + h * WW;
    const int hU = (h == 0)      ? HH - 1 : h - 1;
    const int hD = (h == HH - 1) ? 0      : h + 1;
    const int rowU = base + hU * WW;
    const int rowD = base + hD * WW;

    // vector loads (aligned: w0 multiple of 4)
    const float4 lam  = *reinterpret_cast<const float4*>(lambdak + rowC + w0);
    const float4 lamD = *reinterpret_cast<const float4*>(lambdak + rowD + w0);
    const float4 m    = *reinterpret_cast<const float4*>(mk      + rowC + w0);
    const float4 mU   = *reinterpret_cast<const float4*>(mk      + rowU + w0);
    const float4 mD   = *reinterpret_cast<const float4*>(mk      + rowD + w0);
    const float4 a    = *reinterpret_cast<const float4*>(diagAtA + rowC + w0);
    const float4 ay   = *reinterpret_cast<const float4*>(Aty     + rowC + w0);

    // scalar halo loads in w (circular)
    const int wR = (w0 + 4) & (WW - 1);  // w0+4 mod W
    const int wL = (w0 - 1) & (WW - 1);  // w0-1 mod W
    const float lam_r4 = lambdak[rowC + wR];
    const float m_r4   = mk[rowC + wR];
    const float m_lm1  = mk[rowC + wL];

    // per-lane views (fully unrolled -> registers, compile-time indices)
    const float lamv[5]  = {lam.x, lam.y, lam.z, lam.w, lam_r4};
    const float mv[6]    = {m_lm1, m.x, m.y, m.z, m.w, m_r4};
    const float lamDv[4] = {lamD.x, lamD.y, lamD.z, lamD.w};
    const float mUv[4]   = {mU.x, mU.y, mU.z, mU.w};
    const float mDv[4]   = {mD.x, mD.y, mD.z, mD.w};
    const float av[4]    = {a.x, a.y, a.z, a.w};
    const float ayv[4]   = {ay.x, ay.y, ay.z, ay.w};

    // downsample mask: h%scale==0 (once per thread), w%scale tracked incrementally
    const bool hOnGrid = (h % scale) == 0;
    int rw = w0 % scale;

    float outm[4], outs[4];
#pragma unroll
    for (int i = 0; i < 4; ++i) {
        const float lam_c = lamv[i];
        const float lam_e = lamv[i + 1];   // lambdak[h, w+1]
        const float lam_s = lamDv[i];      // lambdak[h+1, w]
        const float m_c   = mv[i + 1];
        const float m_w   = mv[i];         // mk[h, w-1]
        const float m_e   = mv[i + 2];     // mk[h, w+1]
        const float m_n   = mUv[i];        // mk[h-1, w]
        const float m_s   = mDv[i];        // mk[h+1, w]

        // diagDtlambdakD = (lam + lam_e) + (lam + lam_s)
        const float diagD = 2.0f * lam_c + lam_e + lam_s;
        const float is = fmaxf(gn * av[i] + gp * diagD, 0.0f) + 0.0001f;

        const float atamk = (hOnGrid && (rw == 0)) ? m_c : 0.0f;
        rw++; if (rw == scale) rw = 0;

        // Dht(lam * Dh(mk)) and Dvt(lam * Dv(mk)), expanded:
        const float dh = lam_c * (m_c - m_w) - lam_e * (m_e - m_c);
        const float dv = lam_c * (m_c - m_n) - lam_s * (m_s - m_c);

        const float num = gn * (ayv[i] - atamk + av[i] * m_c)
                        - gp * (dh + dv)
                        + gp * diagD * m_c;
        outm[i] = num / is;
        outs[i] = is;
    }

    *reinterpret_cast<float4*>(out_m_r     + rowC + w0) =
        make_float4(outm[0], outm[1], outm[2], outm[3]);
    *reinterpret_cast<float4*>(out_invSigma + rowC + w0) =
        make_float4(outs[0], outs[1], outs[2], outs[3]);
}

extern "C" void kernel_launch(void* const* d_in, const int* in_sizes, int n_in,
                              void* d_out, int out_size, void* d_ws, size_t ws_size,
                              hipStream_t stream) {
    const float* diagAtA = (const float*)d_in[0];
    const float* Aty     = (const float*)d_in[1];
    const float* mk      = (const float*)d_in[2];
    const float* lambdak = (const float*)d_in[3];
    const float* gamma_n = (const float*)d_in[4];
    const float* gamma_p = (const float*)d_in[5];
    const int*   scale   = (const int*)d_in[6];

    float* out = (float*)d_out;
    const int n = out_size / 2;                  // 8*3*1024*1024
    float* out_m_r      = out;
    float* out_invSigma = out + n;

    const int total_vec = NPLANES * HH * VECS_PER_ROW;
    const int block = 256;
    const int grid = (total_vec + block - 1) / block;
    rmodule_kernel<<<grid, block, 0, stream>>>(
        diagAtA, Aty, mk, lambdak, gamma_n, gamma_p, scale,
        out_m_r, out_invSigma);
}